// Round 2
// baseline (215.987 us; speedup 1.0000x reference)
//
#include <hip/hip_runtime.h>

#define EPS 1e-5f
// B=64, D=2048, E=64, H1=512, H2=256

typedef __attribute__((ext_vector_type(8))) short short8;
typedef __attribute__((ext_vector_type(4))) float f32x4;

__device__ __forceinline__ float bflo(unsigned u) { return __uint_as_float(u << 16); }
__device__ __forceinline__ float bfhi(unsigned u) { return __uint_as_float(u & 0xffff0000u); }
__device__ __forceinline__ unsigned short f2bf(float f) {
  unsigned u = __float_as_uint(f);
  u = u + 0x7FFFu + ((u >> 16) & 1u);  // RNE
  return (unsigned short)(u >> 16);
}
__device__ __forceinline__ unsigned pack2(float a, float b) {
  return (unsigned)f2bf(a) | ((unsigned)f2bf(b) << 16);
}

// ---------------- prep: Q,R (bf16), W2t (bf16 transpose), BN vectors ----------------
__global__ __launch_bounds__(256) void prep(
    const float* __restrict__ emb, const float* __restrict__ W1,
    const float* __restrict__ g1, const float* __restrict__ v1,
    const float* __restrict__ b1, const float* __restrict__ m1,
    const float* __restrict__ beta1,
    const float* __restrict__ W2,
    const float* __restrict__ g2, const float* __restrict__ v2,
    const float* __restrict__ b2, const float* __restrict__ m2,
    const float* __restrict__ beta2,
    unsigned* __restrict__ Q, unsigned* __restrict__ R,
    unsigned short* __restrict__ W2t,
    float* __restrict__ t2, float* __restrict__ c2, float* __restrict__ pbias) {
  const int x = blockIdx.x, t = threadIdx.x;
  if (x < 256) {
    const int k0 = x * 8;
    const int h = t * 2;
    const float a0 = g1[h] * rsqrtf(v1[h] + EPS);
    const float a1 = g1[h + 1] * rsqrtf(v1[h + 1] + EPS);
    const float* We = W1 + 2048 * 512;
    float acc0[8], acc1[8];
    #pragma unroll
    for (int k = 0; k < 8; ++k) { acc0[k] = 0.f; acc1[k] = 0.f; }
    for (int e = 0; e < 64; ++e) {
      float2 wv = *(const float2*)(We + e * 512 + h);
      #pragma unroll
      for (int k = 0; k < 8; ++k) {
        float ev = emb[(k0 + k) * 64 + e];  // wave-uniform -> s_load
        acc0[k] = fmaf(ev, wv.x, acc0[k]);
        acc1[k] = fmaf(ev, wv.y, acc1[k]);
      }
    }
    #pragma unroll
    for (int k = 0; k < 8; ++k) {
      Q[(k0 + k) * 256 + t] = pack2(a0 * acc0[k], a1 * acc1[k]);
      float2 wv = *(const float2*)(W1 + (size_t)(k0 + k) * 512 + h);
      R[(k0 + k) * 256 + t] = pack2(a0 * wv.x, a1 * wv.y);
    }
  } else if (x < 320) {
    const int h0 = (x - 256) * 8;
    const int o = t;
    unsigned d[4];
    #pragma unroll
    for (int i = 0; i < 4; ++i) {
      float v0 = W2[(h0 + 2 * i) * 256 + o];      // coalesced across o
      float v1_ = W2[(h0 + 2 * i + 1) * 256 + o];
      d[i] = pack2(v0, v1_);
    }
    *(uint4*)(W2t + o * 512 + h0) = make_uint4(d[0], d[1], d[2], d[3]);  // 16B/thread
  } else {
    float tv = g2[t] * rsqrtf(v2[t] + EPS);
    t2[t] = tv;
    c2[t] = tv * (b2[t] - m2[t]) + beta2[t];
    #pragma unroll
    for (int i = 0; i < 2; ++i) {
      int h = t + i * 256;
      float a = g1[h] * rsqrtf(v1[h] + EPS);
      pbias[h] = a * (b1[h] - m1[h]) + beta1[h];
    }
  }
}

// ---------------- P = bf16( rep @ R + pbias ) ----------------
__global__ __launch_bounds__(1024) void p_gemm(
    const float* __restrict__ rep, const unsigned* __restrict__ R,
    const float* __restrict__ pbias, unsigned* __restrict__ P) {
  __shared__ float red[16 * 512];
  const int b = blockIdx.x, t = threadIdx.x;
  const int lane = t & 63, kq = t >> 6;  // kq wave-uniform
  const int hl = lane * 8;
  const float* rp = rep + b * 2048 + kq * 128;
  const unsigned* Rp = R + (size_t)(kq * 128) * 256 + lane * 4;
  float acc[8];
  #pragma unroll
  for (int i = 0; i < 8; ++i) acc[i] = 0.f;
  #pragma unroll 4
  for (int k = 0; k < 128; ++k) {
    uint4 rv = *(const uint4*)(Rp + (size_t)k * 256);
    float rk = rp[k];  // wave-uniform scalar
    acc[0] = fmaf(rk, bflo(rv.x), acc[0]); acc[1] = fmaf(rk, bfhi(rv.x), acc[1]);
    acc[2] = fmaf(rk, bflo(rv.y), acc[2]); acc[3] = fmaf(rk, bfhi(rv.y), acc[3]);
    acc[4] = fmaf(rk, bflo(rv.z), acc[4]); acc[5] = fmaf(rk, bfhi(rv.z), acc[5]);
    acc[6] = fmaf(rk, bflo(rv.w), acc[6]); acc[7] = fmaf(rk, bfhi(rv.w), acc[7]);
  }
  *(f32x4*)(&red[kq * 512 + hl])     = (f32x4){acc[0], acc[1], acc[2], acc[3]};
  *(f32x4*)(&red[kq * 512 + hl + 4]) = (f32x4){acc[4], acc[5], acc[6], acc[7]};
  __syncthreads();
  if (t < 256) {
    const int h = t * 2;
    float s0 = 0.f, s1 = 0.f;
    #pragma unroll
    for (int q = 0; q < 16; ++q) { s0 += red[q * 512 + h]; s1 += red[q * 512 + h + 1]; }
    P[b * 256 + t] = pack2(s0 + pbias[h], s1 + pbias[h + 1]);
  }
}

// ---------------- fused main (v2: 512 thr / 8 waves, 64x64 wave tile) ----------------
// Block: 2 k-values x 64 b = 128 rows, N=256 (all o), K=512 in 8 chunks of 64.
// 8 waves: (wm = w>>2) picks row-half, (wn = w&3) picks 64-o column block.
// acc[4][4] = 64 AGPRs/lane -> total regs <=128 -> 4 waves/SIMD (2 blocks/CU).
// A generated into LDS fragment-ordered; gen roles: ks_g = w&1, m2_g = (w>>1)&3.
__global__ __launch_bounds__(512, 4) void fused_main(
    const float* __restrict__ rep,
    const unsigned* __restrict__ P,
    const unsigned* __restrict__ Q,
    const unsigned* __restrict__ Rm,
    const unsigned short* __restrict__ W2t,
    const float* __restrict__ t2, const float* __restrict__ c2,
    const float* __restrict__ W3, const float* __restrict__ b3,
    float* __restrict__ out) {
  __shared__ unsigned short A_lds[2][8192];  // 2 x 16KB, fragment-ordered
  __shared__ float repc[128];
  __shared__ float partial[4][128];

  const int t = threadIdx.x;     // 0..511
  const int w = t >> 6;          // 0..7
  const int ln = t & 15;
  const int lq = (t >> 4) & 3;
  const int ks_g = w & 1;        // gen role: 32-col half
  const int m2_g = (w >> 1) & 3; // gen role: mi = p*4 + m2_g
  const int wn = w & 3;          // mfma role: o block [wn*64, wn*64+64)
  const int wm = w >> 2;         // mfma role: row half (mi_g = wm*4 + mi)
  const int k0 = blockIdx.x * 2;

  if (t < 128) repc[t] = rep[(t & 63) * 2048 + k0 + (t >> 6)];

  f32x4 acc[4][4];
  #pragma unroll
  for (int mi = 0; mi < 4; ++mi)
    #pragma unroll
    for (int nj = 0; nj < 4; ++nj) acc[mi][nj] = (f32x4){0.f, 0.f, 0.f, 0.f};

  __syncthreads();  // repc visible

  // generate chunk c of A (128 rows x 64 cols) into buf, fragment-ordered
  auto gen = [&](int c, unsigned short* buf) {
    const int colbase = c * 64 + ks_g * 32 + lq * 8;
    const int cb2 = colbase >> 1;
    #pragma unroll
    for (int p = 0; p < 2; ++p) {
      const int mi = p * 4 + m2_g;
      const int r = mi * 16 + ln;   // 0..127
      const int bb = r & 63;
      const int kg = k0 + (r >> 6);
      uint4 pv = *(const uint4*)(P + (bb << 8) + cb2);
      uint4 qv = *(const uint4*)(Q + (kg << 8) + cb2);
      uint4 rv = *(const uint4*)(Rm + (kg << 8) + cb2);
      const float rb = repc[r];
      unsigned d[4];
      {
        float z0 = fmaf(-rb, bflo(rv.x), bflo(pv.x) + bflo(qv.x));
        float z1 = fmaf(-rb, bfhi(rv.x), bfhi(pv.x) + bfhi(qv.x));
        d[0] = pack2(fmaxf(z0, 0.f), fmaxf(z1, 0.f));
        z0 = fmaf(-rb, bflo(rv.y), bflo(pv.y) + bflo(qv.y));
        z1 = fmaf(-rb, bfhi(rv.y), bfhi(pv.y) + bfhi(qv.y));
        d[1] = pack2(fmaxf(z0, 0.f), fmaxf(z1, 0.f));
        z0 = fmaf(-rb, bflo(rv.z), bflo(pv.z) + bflo(qv.z));
        z1 = fmaf(-rb, bfhi(rv.z), bfhi(pv.z) + bfhi(qv.z));
        d[2] = pack2(fmaxf(z0, 0.f), fmaxf(z1, 0.f));
        z0 = fmaf(-rb, bflo(rv.w), bflo(pv.w) + bflo(qv.w));
        z1 = fmaf(-rb, bfhi(rv.w), bfhi(pv.w) + bfhi(qv.w));
        d[3] = pack2(fmaxf(z0, 0.f), fmaxf(z1, 0.f));
      }
      // fragment group id = ((mi*2+ks_g)*4+lq)*16 + ln ; 16B per group
      *(uint4*)(&buf[(size_t)((((mi * 2 + ks_g) * 4 + lq) * 16 + ln)) * 8]) =
          make_uint4(d[0], d[1], d[2], d[3]);
    }
  };

  gen(0, A_lds[0]);

  for (int c = 0; c < 8; ++c) {
    __syncthreads();  // writes of buf[c&1] visible; prior reads of buf[(c+1)&1] done
    if (c < 7) gen(c + 1, A_lds[(c + 1) & 1]);
    const unsigned short* buf = A_lds[c & 1];
    #pragma unroll
    for (int ks = 0; ks < 2; ++ks) {
      short8 afr[4];
      #pragma unroll
      for (int mi = 0; mi < 4; ++mi) {
        const int mi_g = wm * 4 + mi;
        afr[mi] = *(const short8*)(buf + (size_t)((((mi_g * 2 + ks) * 4 + lq) * 16 + ln) * 8));
      }
      short8 bfr[4];
      #pragma unroll
      for (int nj = 0; nj < 4; ++nj)
        bfr[nj] = *(const short8*)(W2t + (size_t)(wn * 64 + nj * 16 + ln) * 512 + c * 64 + ks * 32 + lq * 8);
      #pragma unroll
      for (int mi = 0; mi < 4; ++mi)
        #pragma unroll
        for (int nj = 0; nj < 4; ++nj)
          acc[mi][nj] = __builtin_amdgcn_mfma_f32_16x16x32_bf16(afr[mi], bfr[nj], acc[mi][nj], 0, 0, 0);
    }
  }

  // epilogue: u = relu(t2[o]*acc + c2[o]) * W3[o]; reduce over o (nj x ln)
  float t2v[4], c2v[4], w3v[4];
  #pragma unroll
  for (int nj = 0; nj < 4; ++nj) {
    int o = wn * 64 + nj * 16 + ln;
    t2v[nj] = t2[o];
    c2v[nj] = c2[o];
    w3v[nj] = W3[o];
  }
  #pragma unroll
  for (int mi = 0; mi < 4; ++mi) {
    float s[4] = {0.f, 0.f, 0.f, 0.f};
    #pragma unroll
    for (int nj = 0; nj < 4; ++nj)
      #pragma unroll
      for (int r = 0; r < 4; ++r) {
        float u = fmaf(t2v[nj], acc[mi][nj][r], c2v[nj]);
        u = fmaxf(u, 0.f);
        s[r] = fmaf(u, w3v[nj], s[r]);
      }
    #pragma unroll
    for (int r = 0; r < 4; ++r) {
      #pragma unroll
      for (int m = 1; m < 16; m <<= 1) s[r] += __shfl_xor(s[r], m, 64);
    }
    if (ln == 0) {
      #pragma unroll
      for (int r = 0; r < 4; ++r)
        partial[wn][wm * 64 + mi * 16 + lq * 4 + r] = s[r];
    }
  }
  __syncthreads();
  if (t < 128) {
    out[(t & 63) * 2048 + k0 + (t >> 6)] =
        partial[0][t] + partial[1][t] + partial[2][t] + partial[3][t] + b3[0];
  }
}

extern "C" void kernel_launch(void* const* d_in, const int* in_sizes, int n_in,
                              void* d_out, int out_size, void* d_ws, size_t ws_size,
                              hipStream_t stream) {
  const float* rep   = (const float*)d_in[0];
  const float* emb   = (const float*)d_in[1];
  const float* W1    = (const float*)d_in[2];
  const float* b1    = (const float*)d_in[3];
  const float* g1    = (const float*)d_in[4];
  const float* beta1 = (const float*)d_in[5];
  const float* m1    = (const float*)d_in[6];
  const float* v1    = (const float*)d_in[7];
  const float* W2    = (const float*)d_in[8];
  const float* b2    = (const float*)d_in[9];
  const float* g2    = (const float*)d_in[10];
  const float* beta2 = (const float*)d_in[11];
  const float* m2    = (const float*)d_in[12];
  const float* v2    = (const float*)d_in[13];
  const float* W3    = (const float*)d_in[14];
  const float* b3    = (const float*)d_in[15];
  float* out = (float*)d_out;

  char* ws = (char*)d_ws;
  float* t2            = (float*)(ws + 0);        // 256 f32
  float* c2            = (float*)(ws + 1024);     // 256 f32
  float* pbias         = (float*)(ws + 2048);     // 512 f32
  unsigned* P          = (unsigned*)(ws + 4096);     // 64x512 bf16 (pairs)
  unsigned* Q          = (unsigned*)(ws + 69632);    // 2048x512 bf16 (pairs)
  unsigned* R          = (unsigned*)(ws + 2166784);  // 2048x512 bf16 (pairs)
  unsigned short* W2t  = (unsigned short*)(ws + 4263936);  // 256x512 bf16

  prep<<<321, 256, 0, stream>>>(emb, W1, g1, v1, b1, m1, beta1, W2, g2, v2, b2, m2,
                                beta2, Q, R, W2t, t2, c2, pbias);
  p_gemm<<<64, 1024, 0, stream>>>(rep, R, pbias, P);
  fused_main<<<1024, 512, 0, stream>>>(rep, P, Q, R, W2t, t2, c2, W3, b3, out);
}

// Round 3
// 207.305 us; speedup vs baseline: 1.0419x; 1.0419x over previous
//
#include <hip/hip_runtime.h>

#define EPS 1e-5f
// B=64, D=2048, E=64, H1=512, H2=256

typedef __attribute__((ext_vector_type(8))) short short8;
typedef __attribute__((ext_vector_type(4))) float f32x4;

__device__ __forceinline__ float bflo(unsigned u) { return __uint_as_float(u << 16); }
__device__ __forceinline__ float bfhi(unsigned u) { return __uint_as_float(u & 0xffff0000u); }
__device__ __forceinline__ unsigned short f2bf(float f) {
  unsigned u = __float_as_uint(f);
  u = u + 0x7FFFu + ((u >> 16) & 1u);  // RNE
  return (unsigned short)(u >> 16);
}
__device__ __forceinline__ unsigned pack2(float a, float b) {
  return (unsigned)f2bf(a) | ((unsigned)f2bf(b) << 16);
}

// ---------------- prep ----------------
// blocks 0..511   : Q/R for 4 k-values each (emb staged in LDS, no s_load chain)
// blocks 512..575 : W2t[o][h] = bf16(W2[h][o])
// block  576      : t2, c2, and P_f32 init with pbias (pbias baked into P)
__global__ __launch_bounds__(256) void prep(
    const float* __restrict__ emb, const float* __restrict__ W1,
    const float* __restrict__ g1, const float* __restrict__ v1,
    const float* __restrict__ b1, const float* __restrict__ m1,
    const float* __restrict__ beta1,
    const float* __restrict__ W2,
    const float* __restrict__ g2, const float* __restrict__ v2,
    const float* __restrict__ b2, const float* __restrict__ m2,
    const float* __restrict__ beta2,
    unsigned* __restrict__ Q, unsigned* __restrict__ R,
    unsigned short* __restrict__ W2t,
    float* __restrict__ t2, float* __restrict__ c2, float* __restrict__ Pf) {
  __shared__ float emb_s[256];
  __shared__ float pb[512];
  const int x = blockIdx.x, t = threadIdx.x;
  if (x < 512) {
    const int k0 = x * 4;
    emb_s[t] = emb[x * 256 + t];  // 4 emb rows, coalesced
    __syncthreads();
    const int h = t * 2;
    const float a0 = g1[h] * rsqrtf(v1[h] + EPS);
    const float a1 = g1[h + 1] * rsqrtf(v1[h + 1] + EPS);
    const float* We = W1 + 2048 * 512;
    float acc0[4], acc1[4];
    #pragma unroll
    for (int k = 0; k < 4; ++k) { acc0[k] = 0.f; acc1[k] = 0.f; }
    #pragma unroll 4
    for (int e = 0; e < 64; ++e) {
      float2 wv = *(const float2*)(We + e * 512 + h);
      #pragma unroll
      for (int k = 0; k < 4; ++k) {
        float ev = emb_s[k * 64 + e];  // LDS broadcast
        acc0[k] = fmaf(ev, wv.x, acc0[k]);
        acc1[k] = fmaf(ev, wv.y, acc1[k]);
      }
    }
    #pragma unroll
    for (int k = 0; k < 4; ++k) {
      Q[(k0 + k) * 256 + t] = pack2(a0 * acc0[k], a1 * acc1[k]);
      float2 wv = *(const float2*)(W1 + (size_t)(k0 + k) * 512 + h);
      R[(k0 + k) * 256 + t] = pack2(a0 * wv.x, a1 * wv.y);
    }
  } else if (x < 576) {
    const int h0 = (x - 512) * 8;
    const int o = t;
    unsigned d[4];
    #pragma unroll
    for (int i = 0; i < 4; ++i) {
      float v0 = W2[(h0 + 2 * i) * 256 + o];      // coalesced across o
      float v1_ = W2[(h0 + 2 * i + 1) * 256 + o];
      d[i] = pack2(v0, v1_);
    }
    *(uint4*)(W2t + o * 512 + h0) = make_uint4(d[0], d[1], d[2], d[3]);  // 16B/thread
  } else {
    float tv = g2[t] * rsqrtf(v2[t] + EPS);
    t2[t] = tv;
    c2[t] = tv * (b2[t] - m2[t]) + beta2[t];
    #pragma unroll
    for (int i = 0; i < 2; ++i) {
      int h = t + i * 256;
      float a = g1[h] * rsqrtf(v1[h] + EPS);
      pb[h] = a * (b1[h] - m1[h]) + beta1[h];
    }
    __syncthreads();
    // init P_f32[b][h] = pbias[h]; p_gemm atomically accumulates on top
    #pragma unroll 4
    for (int j = 0; j < 128; ++j) {
      int idx = j * 256 + t;
      Pf[idx] = pb[idx & 511];
    }
  }
}

// ---------------- p_gemm: P_f32 += rep @ R  (split-K, atomic f32) ----------------
// grid 512 = 64 b x 8 k-slices; block 256 thr = 4 waves, each wave a 64-k sub-slice.
// Full-CU coverage (2 blocks/CU), 64 loads/thread unroll-8.
__global__ __launch_bounds__(256) void p_gemm(
    const float* __restrict__ rep, const unsigned* __restrict__ R,
    float* __restrict__ Pf) {
  __shared__ float red[4][512];
  const int b = blockIdx.x >> 3, ksl = blockIdx.x & 7;
  const int t = threadIdx.x, lane = t & 63, kq = t >> 6;
  const int kbase = ksl * 256 + kq * 64;
  const unsigned* Rp = R + (size_t)kbase * 256 + lane * 4;
  const float* rp = rep + b * 2048 + kbase;
  float acc[8];
  #pragma unroll
  for (int i = 0; i < 8; ++i) acc[i] = 0.f;
  #pragma unroll 8
  for (int k = 0; k < 64; ++k) {
    uint4 rv = *(const uint4*)(Rp + (size_t)k * 256);
    float rk = rp[k];  // wave-uniform scalar
    acc[0] = fmaf(rk, bflo(rv.x), acc[0]); acc[1] = fmaf(rk, bfhi(rv.x), acc[1]);
    acc[2] = fmaf(rk, bflo(rv.y), acc[2]); acc[3] = fmaf(rk, bfhi(rv.y), acc[3]);
    acc[4] = fmaf(rk, bflo(rv.z), acc[4]); acc[5] = fmaf(rk, bfhi(rv.z), acc[5]);
    acc[6] = fmaf(rk, bflo(rv.w), acc[6]); acc[7] = fmaf(rk, bfhi(rv.w), acc[7]);
  }
  *(f32x4*)(&red[kq][lane * 8])     = (f32x4){acc[0], acc[1], acc[2], acc[3]};
  *(f32x4*)(&red[kq][lane * 8 + 4]) = (f32x4){acc[4], acc[5], acc[6], acc[7]};
  __syncthreads();
  {
    const int h = t * 2;
    float s0 = red[0][h] + red[1][h] + red[2][h] + red[3][h];
    float s1 = red[0][h + 1] + red[1][h + 1] + red[2][h + 1] + red[3][h + 1];
    atomicAdd(&Pf[b * 512 + h], s0);
    atomicAdd(&Pf[b * 512 + h + 1], s1);
  }
}

// ---------------- fused main (v3: grid 2048, 1 k per block, 4 waves, 64x64 tiles) ----------------
// Block: 1 k-value x 64 b = 64 rows, N=256 (all o), K=512 in 8 chunks of 64.
// Wave w: o in [w*64, w*64+64), acc[4][4] = 64 AGPR; gen roles ks_g=w&1, m2_g=(w>>1)&1.
// launch_bounds(256,3): ~154 unified regs -> 3 waves/SIMD, 3 blocks/CU, no spill.
__global__ __launch_bounds__(256, 3) void fused_main(
    const float* __restrict__ rep,
    const float* __restrict__ Pf,
    const unsigned* __restrict__ Q,
    const unsigned* __restrict__ Rm,
    const unsigned short* __restrict__ W2t,
    const float* __restrict__ t2, const float* __restrict__ c2,
    const float* __restrict__ W3, const float* __restrict__ b3,
    float* __restrict__ out) {
  __shared__ unsigned short A_lds[2][4096];  // 2 x 8KB, fragment-ordered
  __shared__ float repc[64];
  __shared__ float partial[4][64];

  const int t = threadIdx.x;     // 0..255
  const int w = t >> 6;          // 0..3 : o block AND gen role
  const int ln = t & 15;
  const int lq = (t >> 4) & 3;
  const int ks_g = w & 1;        // gen role: 32-col half
  const int m2_g = (w >> 1) & 1; // gen role: mi = p*2 + m2_g
  const int k0 = blockIdx.x;     // 0..2047

  if (t < 64) repc[t] = rep[t * 2048 + k0];

  f32x4 acc[4][4];
  #pragma unroll
  for (int mi = 0; mi < 4; ++mi)
    #pragma unroll
    for (int nj = 0; nj < 4; ++nj) acc[mi][nj] = (f32x4){0.f, 0.f, 0.f, 0.f};

  __syncthreads();  // repc visible

  // generate chunk c of A (64 rows x 64 cols) into buf, fragment-ordered
  auto gen = [&](int c, unsigned short* buf) {
    const int colbase = c * 64 + ks_g * 32 + lq * 8;
    const int cb2 = colbase >> 1;
    const uint4 qv = *(const uint4*)(Q + (k0 << 8) + cb2);   // k0-row, shared by both p
    const uint4 rv = *(const uint4*)(Rm + (k0 << 8) + cb2);
    #pragma unroll
    for (int p = 0; p < 2; ++p) {
      const int mi = p * 2 + m2_g;
      const int r = mi * 16 + ln;   // 0..63 == b
      const float4 pv0 = *(const float4*)(Pf + r * 512 + colbase);
      const float4 pv1 = *(const float4*)(Pf + r * 512 + colbase + 4);
      const float rb = repc[r];
      unsigned d[4];
      {
        float z0 = fmaf(-rb, bflo(rv.x), pv0.x + bflo(qv.x));
        float z1 = fmaf(-rb, bfhi(rv.x), pv0.y + bfhi(qv.x));
        d[0] = pack2(fmaxf(z0, 0.f), fmaxf(z1, 0.f));
        z0 = fmaf(-rb, bflo(rv.y), pv0.z + bflo(qv.y));
        z1 = fmaf(-rb, bfhi(rv.y), pv0.w + bfhi(qv.y));
        d[1] = pack2(fmaxf(z0, 0.f), fmaxf(z1, 0.f));
        z0 = fmaf(-rb, bflo(rv.z), pv1.x + bflo(qv.z));
        z1 = fmaf(-rb, bfhi(rv.z), pv1.y + bfhi(qv.z));
        d[2] = pack2(fmaxf(z0, 0.f), fmaxf(z1, 0.f));
        z0 = fmaf(-rb, bflo(rv.w), pv1.z + bflo(qv.w));
        z1 = fmaf(-rb, bfhi(rv.w), pv1.w + bfhi(qv.w));
        d[3] = pack2(fmaxf(z0, 0.f), fmaxf(z1, 0.f));
      }
      // fragment group id = ((mi*2+ks_g)*4+lq)*16 + ln ; 16B per group
      *(uint4*)(&buf[(size_t)(((mi * 2 + ks_g) * 4 + lq) * 16 + ln) * 8]) =
          make_uint4(d[0], d[1], d[2], d[3]);
    }
  };

  gen(0, A_lds[0]);

  for (int c = 0; c < 8; ++c) {
    __syncthreads();  // writes of buf[c&1] visible; prior reads of buf[(c+1)&1] done
    if (c < 7) gen(c + 1, A_lds[(c + 1) & 1]);
    const unsigned short* buf = A_lds[c & 1];
    #pragma unroll
    for (int ks = 0; ks < 2; ++ks) {
      short8 afr[4];
      #pragma unroll
      for (int mi = 0; mi < 4; ++mi)
        afr[mi] = *(const short8*)(buf + (size_t)(((mi * 2 + ks) * 4 + lq) * 16 + ln) * 8);
      short8 bfr[4];
      #pragma unroll
      for (int nj = 0; nj < 4; ++nj)
        bfr[nj] = *(const short8*)(W2t + (size_t)(w * 64 + nj * 16 + ln) * 512 + c * 64 + ks * 32 + lq * 8);
      #pragma unroll
      for (int mi = 0; mi < 4; ++mi)
        #pragma unroll
        for (int nj = 0; nj < 4; ++nj)
          acc[mi][nj] = __builtin_amdgcn_mfma_f32_16x16x32_bf16(afr[mi], bfr[nj], acc[mi][nj], 0, 0, 0);
    }
  }

  // epilogue: u = relu(t2[o]*acc + c2[o]) * W3[o]; reduce over o (nj x ln)
  float t2v[4], c2v[4], w3v[4];
  #pragma unroll
  for (int nj = 0; nj < 4; ++nj) {
    int o = w * 64 + nj * 16 + ln;
    t2v[nj] = t2[o];
    c2v[nj] = c2[o];
    w3v[nj] = W3[o];
  }
  #pragma unroll
  for (int mi = 0; mi < 4; ++mi) {
    float s[4] = {0.f, 0.f, 0.f, 0.f};
    #pragma unroll
    for (int nj = 0; nj < 4; ++nj)
      #pragma unroll
      for (int r = 0; r < 4; ++r) {
        float u = fmaf(t2v[nj], acc[mi][nj][r], c2v[nj]);
        u = fmaxf(u, 0.f);
        s[r] = fmaf(u, w3v[nj], s[r]);
      }
    #pragma unroll
    for (int r = 0; r < 4; ++r) {
      #pragma unroll
      for (int m = 1; m < 16; m <<= 1) s[r] += __shfl_xor(s[r], m, 64);
    }
    if (ln == 0) {
      #pragma unroll
      for (int r = 0; r < 4; ++r)
        partial[w][mi * 16 + lq * 4 + r] = s[r];
    }
  }
  __syncthreads();
  if (t < 64) {
    out[t * 2048 + k0] =
        partial[0][t] + partial[1][t] + partial[2][t] + partial[3][t] + b3[0];
  }
}

extern "C" void kernel_launch(void* const* d_in, const int* in_sizes, int n_in,
                              void* d_out, int out_size, void* d_ws, size_t ws_size,
                              hipStream_t stream) {
  const float* rep   = (const float*)d_in[0];
  const float* emb   = (const float*)d_in[1];
  const float* W1    = (const float*)d_in[2];
  const float* b1    = (const float*)d_in[3];
  const float* g1    = (const float*)d_in[4];
  const float* beta1 = (const float*)d_in[5];
  const float* m1    = (const float*)d_in[6];
  const float* v1    = (const float*)d_in[7];
  const float* W2    = (const float*)d_in[8];
  const float* b2    = (const float*)d_in[9];
  const float* g2    = (const float*)d_in[10];
  const float* beta2 = (const float*)d_in[11];
  const float* m2    = (const float*)d_in[12];
  const float* v2    = (const float*)d_in[13];
  const float* W3    = (const float*)d_in[14];
  const float* b3    = (const float*)d_in[15];
  float* out = (float*)d_out;

  char* ws = (char*)d_ws;
  float* t2            = (float*)(ws + 0);           // 256 f32
  float* c2            = (float*)(ws + 1024);        // 256 f32
  float* Pf            = (float*)(ws + 4096);        // 64x512 f32 (ends 135168)
  unsigned* Q          = (unsigned*)(ws + 135168);   // 2048x512 bf16 pairs (2MB)
  unsigned* R          = (unsigned*)(ws + 2232320);  // 2048x512 bf16 pairs (2MB)
  unsigned short* W2t  = (unsigned short*)(ws + 4329472);  // 256x512 bf16 (256KB)

  prep<<<577, 256, 0, stream>>>(emb, W1, g1, v1, b1, m1, beta1, W2, g2, v2, b2, m2,
                                beta2, Q, R, W2t, t2, c2, Pf);
  p_gemm<<<512, 256, 0, stream>>>(rep, R, Pf);
  fused_main<<<2048, 256, 0, stream>>>(rep, Pf, Q, R, W2t, t2, c2, W3, b3, out);
}